// Round 13
// baseline (142.783 us; speedup 1.0000x reference)
//
#include <hip/hip_runtime.h>

// CloudRasterizerOversample — R13: one-cache-line record groups (CAPC=8)
// + upfront unconditional line loads in accum + tiny overflow path.
// History: R1 global fp32 atomics 171us (23 G/s scattered-atomic wall).
// R6-R10 staged scatter ~35us + dense accum ~8us (best total 115.8us incl
// ~73us harness restore/poison floor). R11/R12 fixed-slot scatter = 23us
// (WIN) but accum 35-42us: interleaved predicated load->use chains were
// latency-serial at 4 blocks/CU. R13: CAPC=8 -> each (bucket,chunk) group
// is exactly one 64B line; accum loads the line as 4 INDEPENDENT dwordx4
// upfront, predicates only the accumulate bodies. Overflow >8/cell (~17K
// records, P~5% of cells) -> per-bucket global region via padded cursors.

#define N_PIX_LO 128
#define NBKT 1024            // 64 v-slices x 16 y-bands (8 rows)
#define TPB  1024            // threads per scatter block
#define PPT  4               // points per thread
#define CHUNK (TPB * PPT)    // 4096 points per chunk
#define CAPC 8               // record slots per (bucket, chunk) = one 64B line
#define OCAP 512             // overflow slots per bucket (mean ~16)
#define MAXCH 2048           // max chunks supported (489 actual)
#define TILE_FLOATS 1024     // accum band tile: 8 x 128

typedef unsigned int u32;
typedef unsigned short u16;
typedef unsigned long long u64;
typedef float vf4 __attribute__((ext_vector_type(4)));
typedef u64 v2u64 __attribute__((ext_vector_type(2)));

constexpr float RCP_PIX = 1.0f / 0.025f;   // correctly-rounded fp32 (== 40.0f)
constexpr float RCP_DV  = 1.0f / 3.125f;   // correctly-rounded fp32

// Reference binning: FOV_HALF_HI=6.3875, PIX_HI=0.025, VEL0_HI=-404.6875,
// DV_HI=3.125 (fp32). Multiply-by-reciprocal differs from IEEE divide by
// <=1 ulp; interior bin flips are weight-continuous, 0-edges sign-exact;
// only the discontinuous 511/255 validity edges get a re-divide guard.
__device__ __forceinline__ bool decode_geom(float vra, float vde, float vve,
    int& cx, int& cy, int& cv, bool& bx, bool& by, bool& bv,
    float& fx, float& fy, float& fv)
{
    float sx = vra + 6.3875f;
    float sy = vde + 6.3875f;
    float sv = vve + 404.6875f;
    float gx = sx * RCP_PIX;
    float gy = sy * RCP_PIX;
    float gv = sv * RCP_DV;
    if (__builtin_expect(fabsf(gx - 511.f) < 1e-3f, 0)) gx = sx / 0.025f;
    if (__builtin_expect(fabsf(gy - 511.f) < 1e-3f, 0)) gy = sy / 0.025f;
    if (__builtin_expect(fabsf(gv - 255.f) < 1e-3f, 0)) gv = sv / 3.125f;
    float fxf = floorf(gx), fyf = floorf(gy), fvf = floorf(gv);
    int ix0 = (int)fxf, iy0 = (int)fyf, iv0 = (int)fvf;
    fx = gx - fxf; fy = gy - fyf; fv = gv - fvf;
    if (ix0 < 0 || ix0 >= 511 || iy0 < 0 || iy0 >= 511 || iv0 < 0 || iv0 >= 255)
        return false;
    cx = ix0 >> 2; cy = iy0 >> 2; cv = iv0 >> 2;
    bx = (ix0 & 3) == 3; by = (iy0 & 3) == 3; bv = (iv0 & 3) == 3;
    return true;
}
// Range note: cy==127 or cv==63 can never have by/bv set (iy0<=510, iv0<=254),
// so y-band/v-slice splits never cross the last bucket. Verified R5-R12.

__device__ __forceinline__ u64 mk_rec(u32 meta, float w)
{
    return (u64)meta | ((u64)__float_as_uint(w) << 32);
}

// meta: fxq[0:10) fyq[10:20) cx[20:27) cyl[27:30) bx[30] by[31]
__global__ __launch_bounds__(TPB) void k_scatter(
    const float* __restrict__ ra, const float* __restrict__ de,
    const float* __restrict__ vel, const float* __restrict__ flux,
    u16* __restrict__ cnt, u64* __restrict__ recs,
    u32* __restrict__ ocur, u64* __restrict__ orecs, int M, int nchunks)
{
    __shared__ u32 hist[NBKT];
    int tid = threadIdx.x;
    int chunk = blockIdx.x;
    hist[tid] = 0;
    __syncthreads();

    int base = chunk * CHUNK;
    float rr[PPT], dd[PPT], vv[PPT], ff[PPT];
    if (base + 4 * tid + 3 < M) {
        int vi = (base >> 2) + tid;
        vf4 r4 = __builtin_nontemporal_load((const vf4*)ra + vi);
        vf4 d4 = __builtin_nontemporal_load((const vf4*)de + vi);
        vf4 v4 = __builtin_nontemporal_load((const vf4*)vel + vi);
        vf4 f4 = __builtin_nontemporal_load((const vf4*)flux + vi);
        rr[0]=r4.x; rr[1]=r4.y; rr[2]=r4.z; rr[3]=r4.w;
        dd[0]=d4.x; dd[1]=d4.y; dd[2]=d4.z; dd[3]=d4.w;
        vv[0]=v4.x; vv[1]=v4.y; vv[2]=v4.z; vv[3]=v4.w;
        ff[0]=f4.x; ff[1]=f4.y; ff[2]=f4.z; ff[3]=f4.w;
    } else {
        #pragma unroll
        for (int k = 0; k < PPT; ++k) {
            int p = base + 4 * tid + k;
            bool ok = p < M;
            rr[k] = ok ? ra[p] : 1e9f;     // 1e9 -> invalid in decode
            dd[k] = ok ? de[p] : 1e9f;
            vv[k] = ok ? vel[p] : 1e9f;
            ff[k] = ok ? flux[p] : 0.f;
        }
    }

    // recs layout: [bucket][chunk][CAPC] -> one 64B line per (bucket,chunk)
    const size_t cbase = (size_t)chunk * CAPC;
    const size_t bstride = (size_t)nchunks * CAPC;

    #pragma unroll
    for (int k = 0; k < PPT; ++k) {
        int cx, cy, cv; bool bx, by, bv; float fx, fy, fv;
        if (!decode_geom(rr[k], dd[k], vv[k], cx, cy, cv, bx, by, bv, fx, fy, fv))
            continue;
        float f = ff[k] * 0.015625f;        // /64 mean-pool folded in
        int band = cy >> 3, cyl = cy & 7;
        u32 q0 = (u32)((cv << 4) + band);
        bool ys = by && (cyl == 7);
        u32 fxq = (u32)(fx * 1023.f + 0.5f);
        u32 fyq = (u32)(fy * 1023.f + 0.5f);
        u32 mb = fxq | (fyq << 10) | ((u32)cx << 20) | (bx ? (1u << 30) : 0u);
        u32 meta0 = mb | ((u32)cyl << 27) | ((by && !ys) ? (1u << 31) : 0u);
        float wy0 = ys ? (1.f - fy) : 1.f;
        float wv0 = bv ? (1.f - fv) : 1.f;
        float w0 = f * wv0;

        u64 r0 = mk_rec(meta0, w0 * wy0);
        u32 s = atomicAdd(&hist[q0], 1u);
        if (s < CAPC) recs[(size_t)q0 * bstride + cbase + s] = r0;
        else {
            u32 op = atomicAdd(&ocur[q0 * 16], 1u);
            if (op < OCAP) orecs[(size_t)q0 * OCAP + op] = r0;
        }
        if (ys) {
            u64 r1 = mk_rec(mb, w0 * fy);
            u32 s2 = atomicAdd(&hist[q0 + 1], 1u);
            if (s2 < CAPC) recs[(size_t)(q0 + 1) * bstride + cbase + s2] = r1;
            else {
                u32 op = atomicAdd(&ocur[(q0 + 1) * 16], 1u);
                if (op < OCAP) orecs[(size_t)(q0 + 1) * OCAP + op] = r1;
            }
        }
        if (bv) {
            float w1 = f * fv;
            u64 r2 = mk_rec(meta0, w1 * wy0);
            u32 s3 = atomicAdd(&hist[q0 + 16], 1u);
            if (s3 < CAPC) recs[(size_t)(q0 + 16) * bstride + cbase + s3] = r2;
            else {
                u32 op = atomicAdd(&ocur[(q0 + 16) * 16], 1u);
                if (op < OCAP) orecs[(size_t)(q0 + 16) * OCAP + op] = r2;
            }
            if (ys) {
                u64 r3 = mk_rec(mb, w1 * fy);
                u32 s4 = atomicAdd(&hist[q0 + 17], 1u);
                if (s4 < CAPC) recs[(size_t)(q0 + 17) * bstride + cbase + s4] = r3;
                else {
                    u32 op = atomicAdd(&ocur[(q0 + 17) * 16], 1u);
                    if (op < OCAP) orecs[(size_t)(q0 + 17) * OCAP + op] = r3;
                }
            }
        }
    }
    __syncthreads();

    u32 c = hist[tid];
    cnt[(size_t)chunk * NBKT + tid] = (u16)(c < CAPC ? c : CAPC);
}

__device__ __forceinline__ void accum_rec(u64 rr, float* tile)
{
    u32 m = (u32)rr;
    float w = __uint_as_float((u32)(rr >> 32));
    float fx = (float)(m & 1023u)         * (1.f / 1023.f);
    float fy = (float)((m >> 10) & 1023u) * (1.f / 1023.f);
    int cx  = (m >> 20) & 127;
    int cyl = (m >> 27) & 7;
    bool bx = (m >> 30) & 1u;
    bool by = (m >> 31) != 0u;
    float wx0 = bx ? (1.f - fx) : 1.f;
    float wy0 = by ? (1.f - fy) : 1.f;
    int idx = cyl * N_PIX_LO + cx;
    atomicAdd(&tile[idx], w * wx0 * wy0);
    if (bx) atomicAdd(&tile[idx + 1], w * fx * wy0);
    if (by) {
        atomicAdd(&tile[idx + N_PIX_LO], w * wx0 * fy);
        if (bx) atomicAdd(&tile[idx + N_PIX_LO + 1], w * fx * fy);
    }
}

// grid = NBKT; block q accumulates its 8x128 band in a 4KB LDS tile.
// Per chunk: load the full 64B group line as 4 independent dwordx4 FIRST
// (no load->use serialization), then predicated accumulate bodies.
__global__ __launch_bounds__(256) void k_accum(
    const u16* __restrict__ cnt, const u64* __restrict__ recs,
    const u32* __restrict__ ocur, const u64* __restrict__ orecs,
    float* __restrict__ out, int nchunks)
{
    __shared__ float tile[TILE_FLOATS];
    __shared__ u16 scnt[MAXCH];
    int q = blockIdx.x, t = threadIdx.x;
    #pragma unroll
    for (int i = t; i < TILE_FLOATS; i += 256) tile[i] = 0.f;
    for (int c = t; c < nchunks; c += 256)
        scnt[c] = cnt[(size_t)c * NBKT + q];
    __syncthreads();

    const v2u64* bp2 = (const v2u64*)(recs + (size_t)q * nchunks * CAPC);
    for (int c = t; c < nchunks; c += 256) {
        int n = scnt[c];
        const v2u64* gp = bp2 + c * (CAPC / 2);
        v2u64 r0 = gp[0];                  // 4 independent 16B loads, all
        v2u64 r1 = gp[1];                  // issued before any use (one
        v2u64 r2 = gp[2];                  // 64B line; garbage slots are
        v2u64 r3 = gp[3];                  // never accumulated)
        if (n > 0) accum_rec(r0.x, tile);
        if (n > 1) accum_rec(r0.y, tile);
        if (n > 2) accum_rec(r1.x, tile);
        if (n > 3) accum_rec(r1.y, tile);
        if (n > 4) accum_rec(r2.x, tile);
        if (n > 5) accum_rec(r2.y, tile);
        if (n > 6) accum_rec(r3.x, tile);
        if (n > 7) accum_rec(r3.y, tile);
    }

    // overflow sweep (mean ~16 records/bucket)
    u32 on = ocur[q * 16];
    if (on > OCAP) on = OCAP;
    const u64* op = orecs + (size_t)q * OCAP;
    for (u32 p = t; p < on; p += 256) accum_rec(op[p], tile);
    __syncthreads();

    vf4* o = (vf4*)(out + (size_t)q * TILE_FLOATS);
    const vf4* t4 = (const vf4*)tile;
    #pragma unroll
    for (int i = t; i < TILE_FLOATS / 4; i += 256)
        __builtin_nontemporal_store(t4[i], o + i);
}

// ---- fallback: direct global-atomic splat (R1) ----
__global__ __launch_bounds__(256) void k_fallback(
    const float* __restrict__ ra, const float* __restrict__ de,
    const float* __restrict__ vel, const float* __restrict__ flux,
    float* __restrict__ out, int M)
{
    int i = blockIdx.x * blockDim.x + threadIdx.x;
    if (i >= M) return;
    int cx, cy, cv; bool bx, by, bv; float fx, fy, fv;
    if (!decode_geom(ra[i], de[i], vel[i], cx, cy, cv, bx, by, bv, fx, fy, fv)) return;
    float f = flux[i] * 0.015625f;
    float wx0 = bx ? (1.f - fx) : 1.f, wy0 = by ? (1.f - fy) : 1.f, wv0 = bv ? (1.f - fv) : 1.f;
    int nx = bx ? 2 : 1, ny = by ? 2 : 1, nv = bv ? 2 : 1;
    for (int a = 0; a < nv; ++a) {
        float wva = a ? fv : wv0;
        for (int b = 0; b < ny; ++b) {
            float wab = f * wva * (b ? fy : wy0);
            int basei = (((cv + a) * N_PIX_LO) + (cy + b)) * N_PIX_LO + cx;
            for (int c = 0; c < nx; ++c)
                atomicAdd(&out[basei + c], wab * (c ? fx : wx0));
        }
    }
}

extern "C" void kernel_launch(void* const* d_in, const int* in_sizes, int n_in,
                              void* d_out, int out_size, void* d_ws, size_t ws_size,
                              hipStream_t stream) {
    const float* ra   = (const float*)d_in[0];
    const float* de   = (const float*)d_in[1];
    const float* vel  = (const float*)d_in[2];
    const float* flux = (const float*)d_in[3];
    float* out = (float*)d_out;
    int M = in_sizes[0];

    int nchunks = (M + CHUNK - 1) / CHUNK;

    // ws layout:
    //   cnt   @ 0       : nchunks*1024 u16   (<= 4 MB for MAXCH)
    //   ocur  @ 4 MB    : 1024 cursors, 64B-padded (64 KB)
    //   orecs @ 4MB+64KB: 1024 * OCAP * 8 B  (4 MB)
    //   recs  @ 8MB+64KB: 1024 * nchunks * 8 * 8 B (~32 MB @489)
    const size_t ocur_off  = 4u << 20;
    const size_t orecs_off = (4u << 20) + 65536;
    const size_t recs_off  = (8u << 20) + 65536;
    const size_t need = recs_off + (size_t)NBKT * nchunks * CAPC * sizeof(u64);

    if (nchunks <= MAXCH && ws_size >= need) {
        u16* cnt   = (u16*)d_ws;
        u32* ocur  = (u32*)((char*)d_ws + ocur_off);
        u64* orecs = (u64*)((char*)d_ws + orecs_off);
        u64* recs  = (u64*)((char*)d_ws + recs_off);
        (void)hipMemsetAsync(ocur, 0, 65536, stream);
        k_scatter<<<nchunks, TPB, 0, stream>>>(ra, de, vel, flux, cnt, recs,
                                               ocur, orecs, M, nchunks);
        k_accum<<<NBKT, 256, 0, stream>>>(cnt, recs, ocur, orecs, out, nchunks);
    } else {
        (void)hipMemsetAsync(out, 0, (size_t)out_size * sizeof(float), stream);
        int grid = (M + 255) / 256;
        k_fallback<<<grid, 256, 0, stream>>>(ra, de, vel, flux, out, M);
    }
}

// Round 14
// 131.191 us; speedup vs baseline: 1.0884x; 1.0884x over previous
//
#include <hip/hip_runtime.h>

// CloudRasterizerOversample — R14: R12's scatter (verbatim; 23us, reproduced
// twice) + R13's upfront-line-load accum (proven structure) on CAPC=24.
// History: R1 global fp32 atomics 171us (23 G/s scattered-atomic wall).
// R6-R10 staged scatter ~35us (tweaks neutral/regress). R11/R12 fixed-slot
// scatter = 23us WIN, but accum 35-42us: ~7 dependent (load->use) HBM
// chains per chunk-group = ~25us serialized latency. R13 fixed accum's
// chains (upfront independent line loads) but poisoned the scatter with
// device-scope overflow cursors (-> 49us, R10 anti-pattern). R14 = good
// scatter + good accum: slots 0-7 of each (bucket,chunk) group are one
// 64B-aligned line (192B group stride), loaded as 4 INDEPENDENT v2u64
// before any use; slots 8..n (P~5%) in a rare tail loop.

#define N_PIX_LO 128
#define NBKT 1024            // 64 v-slices x 16 y-bands (8 rows)
#define TPB  1024            // threads per scatter block
#define PPT  4               // points per thread
#define CHUNK (TPB * PPT)    // 4096 points per chunk
#define CAPC 24              // record slots per (bucket, chunk)
#define MAXCH 2048           // max chunks supported (489 actual)
#define TILE_FLOATS 1024     // accum band tile: 8 x 128

typedef unsigned int u32;
typedef unsigned short u16;
typedef unsigned long long u64;
typedef float vf4 __attribute__((ext_vector_type(4)));
typedef u64 v2u64 __attribute__((ext_vector_type(2)));

constexpr float RCP_PIX = 1.0f / 0.025f;   // correctly-rounded fp32 (== 40.0f)
constexpr float RCP_DV  = 1.0f / 3.125f;   // correctly-rounded fp32

// Reference binning: FOV_HALF_HI=6.3875, PIX_HI=0.025, VEL0_HI=-404.6875,
// DV_HI=3.125 (fp32). Multiply-by-reciprocal differs from IEEE divide by
// <=1 ulp; interior bin flips are weight-continuous, 0-edges sign-exact;
// only the discontinuous 511/255 validity edges get a re-divide guard.
__device__ __forceinline__ bool decode_geom(float vra, float vde, float vve,
    int& cx, int& cy, int& cv, bool& bx, bool& by, bool& bv,
    float& fx, float& fy, float& fv)
{
    float sx = vra + 6.3875f;
    float sy = vde + 6.3875f;
    float sv = vve + 404.6875f;
    float gx = sx * RCP_PIX;
    float gy = sy * RCP_PIX;
    float gv = sv * RCP_DV;
    if (__builtin_expect(fabsf(gx - 511.f) < 1e-3f, 0)) gx = sx / 0.025f;
    if (__builtin_expect(fabsf(gy - 511.f) < 1e-3f, 0)) gy = sy / 0.025f;
    if (__builtin_expect(fabsf(gv - 255.f) < 1e-3f, 0)) gv = sv / 3.125f;
    float fxf = floorf(gx), fyf = floorf(gy), fvf = floorf(gv);
    int ix0 = (int)fxf, iy0 = (int)fyf, iv0 = (int)fvf;
    fx = gx - fxf; fy = gy - fyf; fv = gv - fvf;
    if (ix0 < 0 || ix0 >= 511 || iy0 < 0 || iy0 >= 511 || iv0 < 0 || iv0 >= 255)
        return false;
    cx = ix0 >> 2; cy = iy0 >> 2; cv = iv0 >> 2;
    bx = (ix0 & 3) == 3; by = (iy0 & 3) == 3; bv = (iv0 & 3) == 3;
    return true;
}

__device__ __forceinline__ u64 mk_rec(u32 meta, float w)
{
    return (u64)meta | ((u64)__float_as_uint(w) << 32);
}

// meta: fxq[0:10) fyq[10:20) cx[20:27) cyl[27:30) bx[30] by[31]
__global__ __launch_bounds__(TPB) void k_scatter(
    const float* __restrict__ ra, const float* __restrict__ de,
    const float* __restrict__ vel, const float* __restrict__ flux,
    u16* __restrict__ cnt, u64* __restrict__ recs, int M, int nchunks)
{
    __shared__ u32 hist[NBKT];
    int tid = threadIdx.x;
    int chunk = blockIdx.x;
    hist[tid] = 0;
    __syncthreads();

    int base = chunk * CHUNK;
    float rr[PPT], dd[PPT], vv[PPT], ff[PPT];
    if (base + 4 * tid + 3 < M) {
        int vi = (base >> 2) + tid;
        vf4 r4 = __builtin_nontemporal_load((const vf4*)ra + vi);
        vf4 d4 = __builtin_nontemporal_load((const vf4*)de + vi);
        vf4 v4 = __builtin_nontemporal_load((const vf4*)vel + vi);
        vf4 f4 = __builtin_nontemporal_load((const vf4*)flux + vi);
        rr[0]=r4.x; rr[1]=r4.y; rr[2]=r4.z; rr[3]=r4.w;
        dd[0]=d4.x; dd[1]=d4.y; dd[2]=d4.z; dd[3]=d4.w;
        vv[0]=v4.x; vv[1]=v4.y; vv[2]=v4.z; vv[3]=v4.w;
        ff[0]=f4.x; ff[1]=f4.y; ff[2]=f4.z; ff[3]=f4.w;
    } else {
        #pragma unroll
        for (int k = 0; k < PPT; ++k) {
            int p = base + 4 * tid + k;
            bool ok = p < M;
            rr[k] = ok ? ra[p] : 1e9f;     // 1e9 -> invalid in decode
            dd[k] = ok ? de[p] : 1e9f;
            vv[k] = ok ? vel[p] : 1e9f;
            ff[k] = ok ? flux[p] : 0.f;
        }
    }

    // recs layout: [bucket][chunk][CAPC]; 192B group stride (64B aligned)
    const size_t cbase = (size_t)chunk * CAPC;
    const size_t bstride = (size_t)nchunks * CAPC;

    #pragma unroll
    for (int k = 0; k < PPT; ++k) {
        int cx, cy, cv; bool bx, by, bv; float fx, fy, fv;
        if (!decode_geom(rr[k], dd[k], vv[k], cx, cy, cv, bx, by, bv, fx, fy, fv))
            continue;
        float f = ff[k] * 0.015625f;        // /64 mean-pool folded in
        int band = cy >> 3, cyl = cy & 7;
        u32 q0 = (u32)((cv << 4) + band);
        bool ys = by && (cyl == 7);
        u32 fxq = (u32)(fx * 1023.f + 0.5f);
        u32 fyq = (u32)(fy * 1023.f + 0.5f);
        u32 mb = fxq | (fyq << 10) | ((u32)cx << 20) | (bx ? (1u << 30) : 0u);
        u32 meta0 = mb | ((u32)cyl << 27) | ((by && !ys) ? (1u << 31) : 0u);
        float wy0 = ys ? (1.f - fy) : 1.f;
        float wv0 = bv ? (1.f - fv) : 1.f;
        float w0 = f * wv0;

        u32 s = atomicAdd(&hist[q0], 1u);
        if (s < CAPC) recs[(size_t)q0 * bstride + cbase + s] = mk_rec(meta0, w0 * wy0);
        if (ys) {
            u32 s2 = atomicAdd(&hist[q0 + 1], 1u);
            if (s2 < CAPC) recs[(size_t)(q0 + 1) * bstride + cbase + s2] = mk_rec(mb, w0 * fy);
        }
        if (bv) {
            float w1 = f * fv;
            u32 s3 = atomicAdd(&hist[q0 + 16], 1u);
            if (s3 < CAPC) recs[(size_t)(q0 + 16) * bstride + cbase + s3] = mk_rec(meta0, w1 * wy0);
            if (ys) {
                u32 s4 = atomicAdd(&hist[q0 + 17], 1u);
                if (s4 < CAPC) recs[(size_t)(q0 + 17) * bstride + cbase + s4] = mk_rec(mb, w1 * fy);
            }
        }
    }
    __syncthreads();

    u32 c = hist[tid];
    cnt[(size_t)chunk * NBKT + tid] = (u16)(c < CAPC ? c : CAPC);
}

__device__ __forceinline__ void accum_rec(u64 rr, float* tile)
{
    u32 m = (u32)rr;
    float w = __uint_as_float((u32)(rr >> 32));
    float fx = (float)(m & 1023u)         * (1.f / 1023.f);
    float fy = (float)((m >> 10) & 1023u) * (1.f / 1023.f);
    int cx  = (m >> 20) & 127;
    int cyl = (m >> 27) & 7;
    bool bx = (m >> 30) & 1u;
    bool by = (m >> 31) != 0u;
    float wx0 = bx ? (1.f - fx) : 1.f;
    float wy0 = by ? (1.f - fy) : 1.f;
    int idx = cyl * N_PIX_LO + cx;
    atomicAdd(&tile[idx], w * wx0 * wy0);
    if (bx) atomicAdd(&tile[idx + 1], w * fx * wy0);
    if (by) {
        atomicAdd(&tile[idx + N_PIX_LO], w * wx0 * fy);
        if (bx) atomicAdd(&tile[idx + N_PIX_LO + 1], w * fx * fy);
    }
}

// grid = NBKT; block q accumulates its 8x128 band in a 4KB LDS tile.
// Per chunk: load the group's FIRST 64B line as 4 independent v2u64 before
// any use (covers n<=8, ~95% of cells); predicated accumulate bodies; rare
// tail loop for slots 8..n.
__global__ __launch_bounds__(256) void k_accum(
    const u16* __restrict__ cnt, const u64* __restrict__ recs,
    float* __restrict__ out, int nchunks)
{
    __shared__ float tile[TILE_FLOATS];
    __shared__ u16 scnt[MAXCH];
    int q = blockIdx.x, t = threadIdx.x;
    #pragma unroll
    for (int i = t; i < TILE_FLOATS; i += 256) tile[i] = 0.f;
    for (int c = t; c < nchunks; c += 256)
        scnt[c] = cnt[(size_t)c * NBKT + q];
    __syncthreads();

    const u64* bp = recs + (size_t)q * nchunks * CAPC;
    for (int c = t; c < nchunks; c += 256) {
        int n = scnt[c];
        const u64* gp = bp + (size_t)c * CAPC;
        const v2u64* gp2 = (const v2u64*)gp;
        v2u64 r0 = gp2[0];                 // 4 independent 16B loads (one
        v2u64 r1 = gp2[1];                 // aligned 64B line), all issued
        v2u64 r2 = gp2[2];                 // before any use
        v2u64 r3 = gp2[3];
        if (n > 0) accum_rec(r0.x, tile);
        if (n > 1) accum_rec(r0.y, tile);
        if (n > 2) accum_rec(r1.x, tile);
        if (n > 3) accum_rec(r1.y, tile);
        if (n > 4) accum_rec(r2.x, tile);
        if (n > 5) accum_rec(r2.y, tile);
        if (n > 6) accum_rec(r3.x, tile);
        if (n > 7) accum_rec(r3.y, tile);
        if (__builtin_expect(n > 8, 0)) {  // ~5% of cells
            for (int j = 8; j < n; ++j) accum_rec(gp[j], tile);
        }
    }
    __syncthreads();

    vf4* o = (vf4*)(out + (size_t)q * TILE_FLOATS);
    const vf4* t4 = (const vf4*)tile;
    #pragma unroll
    for (int i = t; i < TILE_FLOATS / 4; i += 256)
        __builtin_nontemporal_store(t4[i], o + i);
}

// ---- fallback: direct global-atomic splat (R1) ----
__global__ __launch_bounds__(256) void k_fallback(
    const float* __restrict__ ra, const float* __restrict__ de,
    const float* __restrict__ vel, const float* __restrict__ flux,
    float* __restrict__ out, int M)
{
    int i = blockIdx.x * blockDim.x + threadIdx.x;
    if (i >= M) return;
    int cx, cy, cv; bool bx, by, bv; float fx, fy, fv;
    if (!decode_geom(ra[i], de[i], vel[i], cx, cy, cv, bx, by, bv, fx, fy, fv)) return;
    float f = flux[i] * 0.015625f;
    float wx0 = bx ? (1.f - fx) : 1.f, wy0 = by ? (1.f - fy) : 1.f, wv0 = bv ? (1.f - fv) : 1.f;
    int nx = bx ? 2 : 1, ny = by ? 2 : 1, nv = bv ? 2 : 1;
    for (int a = 0; a < nv; ++a) {
        float wva = a ? fv : wv0;
        for (int b = 0; b < ny; ++b) {
            float wab = f * wva * (b ? fy : wy0);
            int basei = (((cv + a) * N_PIX_LO) + (cy + b)) * N_PIX_LO + cx;
            for (int c = 0; c < nx; ++c)
                atomicAdd(&out[basei + c], wab * (c ? fx : wx0));
        }
    }
}

extern "C" void kernel_launch(void* const* d_in, const int* in_sizes, int n_in,
                              void* d_out, int out_size, void* d_ws, size_t ws_size,
                              hipStream_t stream) {
    const float* ra   = (const float*)d_in[0];
    const float* de   = (const float*)d_in[1];
    const float* vel  = (const float*)d_in[2];
    const float* flux = (const float*)d_in[3];
    float* out = (float*)d_out;
    int M = in_sizes[0];

    int nchunks = (M + CHUNK - 1) / CHUNK;

    // ws: cnt (nchunks x 1024 u16, reserve 8MB) | recs [1024][nchunks][24] u64
    const size_t recs_off = 8u << 20;
    const size_t need = recs_off + (size_t)NBKT * nchunks * CAPC * sizeof(u64);

    if (nchunks <= MAXCH && ws_size >= need) {
        u16* cnt  = (u16*)d_ws;
        u64* recs = (u64*)((char*)d_ws + recs_off);
        k_scatter<<<nchunks, TPB, 0, stream>>>(ra, de, vel, flux, cnt, recs,
                                               M, nchunks);
        k_accum<<<NBKT, 256, 0, stream>>>(cnt, recs, out, nchunks);
    } else {
        (void)hipMemsetAsync(out, 0, (size_t)out_size * sizeof(float), stream);
        int grid = (M + 255) / 256;
        k_fallback<<<grid, 256, 0, stream>>>(ra, de, vel, flux, out, M);
    }
}